// Round 3
// baseline (456.243 us; speedup 1.0000x reference)
//
#include <hip/hip_runtime.h>
#include <cmath>

// EstimatorQNNGen275: conv+sigmoid+mean -> 1-dim attention -> 4-layer tanh MLP
// (3x 512x4096x4096 GEMMs via fp16 MFMA, split-K=8 + register prefetch) ->
// pairwise-fidelity graph.
//
// ws layout (bytes):
//   [0,2048)     c_buf (512 f32)
//   [2048,4096)  attn  (512 f32)
//   [4096,4736)  D     (10 dot accumulators, line-padded stride 16 f32)
//   [8192,+8MB)  act1 ; act2 ; act3 ; part (Z x 8MB split-K partials)

#define NEL (512 * 4096)

typedef float  floatx4 __attribute__((ext_vector_type(4)));
typedef _Float16 halfx8 __attribute__((ext_vector_type(8)));

// ---------------- conv + sigmoid + mean ----------------
__global__ __launch_bounds__(256) void conv_mean_kernel(
    const float* __restrict__ x, const float* __restrict__ cw,
    const float* __restrict__ cb, float* __restrict__ c_out)
{
  __shared__ float sbuf[4];
  const int b = blockIdx.x;
  const float w00 = cw[0], w01 = cw[1], w10 = cw[2], w11 = cw[3];
  const float bias = cb[0];
  const float* xb = x + (size_t)b * 128 * 128;
  float acc = 0.f;
  for (int idx = threadIdx.x; idx < 127 * 127; idx += 256) {
    int i = idx / 127;
    int j = idx - i * 127;
    const float* p = xb + i * 128 + j;
    float v = w00 * p[0] + w01 * p[1] + w10 * p[128] + w11 * p[129] + bias;
    acc += 1.0f / (1.0f + __expf(-v));
  }
  #pragma unroll
  for (int off = 32; off > 0; off >>= 1) acc += __shfl_down(acc, off, 64);
  const int lane = threadIdx.x & 63, wv = threadIdx.x >> 6;
  if (lane == 0) sbuf[wv] = acc;
  __syncthreads();
  if (threadIdx.x == 0)
    c_out[b] = (sbuf[0] + sbuf[1] + sbuf[2] + sbuf[3]) * (1.0f / 16129.0f);
}

// ---------------- 1-dim attention ----------------
__global__ __launch_bounds__(64) void attn_kernel(
    const float* __restrict__ c, const float* __restrict__ rot,
    const float* __restrict__ ent, float* __restrict__ attn)
{
  const int i = blockIdx.x;
  const int lane = threadIdx.x;
  const float t = rot[0] * ent[0] * c[i];
  float vals[8], cj[8];
  float mx = -1e30f;
  #pragma unroll
  for (int u = 0; u < 8; ++u) {
    float cv = c[lane + u * 64];
    cj[u] = cv;
    vals[u] = t * cv;
    mx = fmaxf(mx, vals[u]);
  }
  #pragma unroll
  for (int off = 32; off > 0; off >>= 1) mx = fmaxf(mx, __shfl_down(mx, off, 64));
  mx = __shfl(mx, 0, 64);
  float se = 0.f, sw = 0.f;
  #pragma unroll
  for (int u = 0; u < 8; ++u) {
    float e = __expf(vals[u] - mx);
    se += e;
    sw += e * cj[u];
  }
  #pragma unroll
  for (int off = 32; off > 0; off >>= 1) {
    se += __shfl_down(se, off, 64);
    sw += __shfl_down(sw, off, 64);
  }
  if (lane == 0) attn[i] = sw / se;
}

// ---------------- layer 1 (outer product + tanh) ----------------
__global__ __launch_bounds__(256) void layer1_kernel(
    const float* __restrict__ attn, const float* __restrict__ W1,
    const float* __restrict__ b1, float* __restrict__ act1)
{
  const int o = blockIdx.x * 256 + threadIdx.x;
  const int i = blockIdx.y;
  act1[(size_t)i * 4096 + o] = tanhf(attn[i] * W1[o] + b1[o]);
}

// ---------------- fp16-MFMA GEMM (split-K, register prefetch) ----------------
// A: M x K fp32 row-major (M=512), W: N x K fp32 row-major (4096x4096).
// 128x128 tile, BK=32, 256 thr = 4 waves (2x2), wave = 64x64 = 4x4 mfma tiles.
// FUSE=true: full-K, epilogue bias+tanh -> C.
// FUSE=false: K-slice per blockIdx.z, raw fp32 partial -> C + z*NEL.
#define BM 128
#define BN 128
#define BK 32
#define LDK 40  // padded leading dim (halfs): 80B stride

template<bool FUSE>
__global__ __launch_bounds__(256) void gemm_tanh_kernel(
    const float* __restrict__ A, const float* __restrict__ W,
    const float* __restrict__ bias, float* __restrict__ C)
{
  __shared__ _Float16 As[BM][LDK];
  __shared__ _Float16 Ws[BN][LDK];
  const int K = 4096, N = 4096;
  const int tid  = threadIdx.x;
  const int lane = tid & 63;
  const int wave = tid >> 6;
  const int wm = (wave >> 1) * 64;
  const int wn = (wave & 1) * 64;
  const int q  = lane >> 4;
  const int ml = lane & 15;
  const int tileM = blockIdx.y * BM;
  const int tileN = blockIdx.x * BN;
  const int Kslice = K / gridDim.z;
  const int kbeg = blockIdx.z * Kslice;
  const int kend = kbeg + Kslice;
  float* Cb = FUSE ? C : C + (size_t)blockIdx.z * NEL;

  floatx4 acc[4][4] = {};

  // staging chunk map: per array, 512 chunks of 8 halfs; thread handles
  // chunks tid and tid+256. chunk c -> row c>>2, cols (c&3)*8 .. +8.
  const int r0  = tid >> 2;            // rows r0 and r0+64
  const int cc0 = (tid & 3) << 3;      // col start

  float4 pa[4], pw[4];  // prefetch regs: [chunk][2x float4]
  auto load_tile = [&](int k0) {
    #pragma unroll
    for (int u = 0; u < 2; ++u) {
      const float* ap = A + (size_t)(tileM + r0 + u * 64) * K + k0 + cc0;
      pa[2 * u]     = *reinterpret_cast<const float4*>(ap);
      pa[2 * u + 1] = *reinterpret_cast<const float4*>(ap + 4);
      const float* wp = W + (size_t)(tileN + r0 + u * 64) * K + k0 + cc0;
      pw[2 * u]     = *reinterpret_cast<const float4*>(wp);
      pw[2 * u + 1] = *reinterpret_cast<const float4*>(wp + 4);
    }
  };
  auto store_tile = [&]() {
    #pragma unroll
    for (int u = 0; u < 2; ++u) {
      halfx8 ha = { (_Float16)pa[2*u].x, (_Float16)pa[2*u].y,
                    (_Float16)pa[2*u].z, (_Float16)pa[2*u].w,
                    (_Float16)pa[2*u+1].x, (_Float16)pa[2*u+1].y,
                    (_Float16)pa[2*u+1].z, (_Float16)pa[2*u+1].w };
      *reinterpret_cast<halfx8*>(&As[r0 + u * 64][cc0]) = ha;
      halfx8 hw = { (_Float16)pw[2*u].x, (_Float16)pw[2*u].y,
                    (_Float16)pw[2*u].z, (_Float16)pw[2*u].w,
                    (_Float16)pw[2*u+1].x, (_Float16)pw[2*u+1].y,
                    (_Float16)pw[2*u+1].z, (_Float16)pw[2*u+1].w };
      *reinterpret_cast<halfx8*>(&Ws[r0 + u * 64][cc0]) = hw;
    }
  };

  load_tile(kbeg);
  for (int k0 = kbeg; k0 < kend; k0 += BK) {
    __syncthreads();     // previous iter's LDS consumers done
    store_tile();
    __syncthreads();
    if (k0 + BK < kend) load_tile(k0 + BK);  // in-flight across MFMA below

    halfx8 af[4], bf[4];
    #pragma unroll
    for (int i = 0; i < 4; ++i)
      af[i] = *reinterpret_cast<const halfx8*>(&As[wm + i * 16 + ml][q * 8]);
    #pragma unroll
    for (int j = 0; j < 4; ++j)
      bf[j] = *reinterpret_cast<const halfx8*>(&Ws[wn + j * 16 + ml][q * 8]);

    #pragma unroll
    for (int i = 0; i < 4; ++i)
      #pragma unroll
      for (int j = 0; j < 4; ++j)
        acc[i][j] = __builtin_amdgcn_mfma_f32_16x16x32_f16(af[i], bf[j], acc[i][j], 0, 0, 0);
  }

  // C/D layout: col=lane&15, row=(lane>>4)*4+reg
  #pragma unroll
  for (int i = 0; i < 4; ++i) {
    const int row0 = tileM + wm + i * 16 + q * 4;
    #pragma unroll
    for (int j = 0; j < 4; ++j) {
      const int col = tileN + wn + j * 16 + ml;
      if (FUSE) {
        const float bv = bias[col];
        #pragma unroll
        for (int r = 0; r < 4; ++r)
          Cb[(size_t)(row0 + r) * N + col] = tanhf(acc[i][j][r] + bv);
      } else {
        #pragma unroll
        for (int r = 0; r < 4; ++r)
          Cb[(size_t)(row0 + r) * N + col] = acc[i][j][r];
      }
    }
  }
}

// ---------------- split-K combine: sum S slices + bias + tanh ----------------
template<int S>
__global__ __launch_bounds__(256) void combine_tanh_kernel(
    const float* __restrict__ part, const float* __restrict__ bias,
    float* __restrict__ outp)
{
  const int i4 = blockIdx.x * 256 + threadIdx.x;  // < NEL/4
  const floatx4* p4 = (const floatx4*)part;
  floatx4 s = p4[i4];
  #pragma unroll
  for (int z = 1; z < S; ++z) s += p4[(size_t)z * (NEL / 4) + i4];
  const floatx4 bv = ((const floatx4*)bias)[i4 & 1023];
  floatx4 o;
  #pragma unroll
  for (int r = 0; r < 4; ++r) o[r] = tanhf(s[r] + bv[r]);
  ((floatx4*)outp)[i4] = o;
}

// ---------------- fid pairwise dots (low-contention) ----------------
__global__ __launch_bounds__(256) void fid_dots_kernel(
    const float* __restrict__ a1, const float* __restrict__ a2,
    const float* __restrict__ a3, const float* __restrict__ a4,
    float* __restrict__ D)
{
  __shared__ float sred[4][10];
  float s[10] = {0, 0, 0, 0, 0, 0, 0, 0, 0, 0};
  const int n4 = NEL / 4;
  const int stride = gridDim.x * blockDim.x;
  const floatx4* p1 = (const floatx4*)a1;
  const floatx4* p2 = (const floatx4*)a2;
  const floatx4* p3 = (const floatx4*)a3;
  const floatx4* p4 = (const floatx4*)a4;
  for (int i = blockIdx.x * 256 + threadIdx.x; i < n4; i += stride) {
    floatx4 v1 = p1[i], v2 = p2[i], v3 = p3[i], v4 = p4[i];
    #pragma unroll
    for (int r = 0; r < 4; ++r) {
      s[0] += v1[r] * v1[r]; s[1] += v1[r] * v2[r]; s[2] += v1[r] * v3[r];
      s[3] += v1[r] * v4[r]; s[4] += v2[r] * v2[r]; s[5] += v2[r] * v3[r];
      s[6] += v2[r] * v4[r]; s[7] += v3[r] * v3[r]; s[8] += v3[r] * v4[r];
      s[9] += v4[r] * v4[r];
    }
  }
  const int lane = threadIdx.x & 63, wv = threadIdx.x >> 6;
  #pragma unroll
  for (int p = 0; p < 10; ++p) {
    float v = s[p];
    #pragma unroll
    for (int off = 32; off > 0; off >>= 1) v += __shfl_down(v, off, 64);
    if (lane == 0) sred[wv][p] = v;
  }
  __syncthreads();
  if (threadIdx.x < 10) {
    float v = sred[0][threadIdx.x] + sred[1][threadIdx.x] +
              sred[2][threadIdx.x] + sred[3][threadIdx.x];
    atomicAdd(&D[threadIdx.x * 16], v);
  }
}

// ---------------- finalize graph weights ----------------
__global__ void finalize_kernel(const float* __restrict__ D, float* __restrict__ wout)
{
  const int i = threadIdx.x;
  if (i >= 16) return;
  const int p = i >> 2, qq = i & 3;
  const int a = p < qq ? p : qq;
  const int b = p < qq ? qq : p;
  const int base[4] = {0, 4, 7, 9};
  const float dpq = D[(base[a] + (b - a)) * 16];
  const float npv = sqrtf(D[base[p] * 16]) + 1e-12f;
  const float nqv = sqrtf(D[base[qq] * 16]) + 1e-12f;
  const float ch = dpq / (npv * nqv);
  const float fid = ch * ch;
  wout[i] = (fid >= 0.8f && p != qq) ? 1.0f : 0.0f;
}

extern "C" void kernel_launch(void* const* d_in, const int* in_sizes, int n_in,
                              void* d_out, int out_size, void* d_ws, size_t ws_size,
                              hipStream_t stream)
{
  const float* x   = (const float*)d_in[0];
  const float* cw  = (const float*)d_in[1];
  const float* cb  = (const float*)d_in[2];
  const float* rot = (const float*)d_in[3];
  const float* ent = (const float*)d_in[4];
  const float* W1  = (const float*)d_in[5];
  const float* b1  = (const float*)d_in[6];
  const float* W2  = (const float*)d_in[7];
  const float* b2  = (const float*)d_in[8];
  const float* W3  = (const float*)d_in[9];
  const float* b3  = (const float*)d_in[10];
  const float* W4  = (const float*)d_in[11];
  const float* b4  = (const float*)d_in[12];
  float* out = (float*)d_out;

  char*  ws    = (char*)d_ws;
  float* c_buf = (float*)(ws + 0);
  float* attn  = (float*)(ws + 2048);
  float* D     = (float*)(ws + 4096);
  float* act1  = (float*)(ws + 8192);
  float* act2  = act1 + NEL;
  float* act3  = act2 + NEL;
  float* part  = act3 + NEL;  // Z x NEL fp32 split-K partials
  float* wout  = out + NEL;

  const size_t base_need = 8192 + (size_t)3 * NEL * 4;
  const bool sk8 = ws_size >= base_need + (size_t)8 * NEL * 4;
  const bool sk4 = ws_size >= base_need + (size_t)4 * NEL * 4;

  hipMemsetAsync(D, 0, 10 * 16 * sizeof(float), stream);
  conv_mean_kernel<<<512, 256, 0, stream>>>(x, cw, cb, c_buf);
  attn_kernel<<<512, 64, 0, stream>>>(c_buf, rot, ent, attn);
  layer1_kernel<<<dim3(16, 512), 256, 0, stream>>>(attn, W1, b1, act1);

  const int cgrid = NEL / 4 / 256;
  if (sk8) {
    dim3 g(4096 / BN, 512 / BM, 8);  // 1024 blocks -> 4 blocks/CU
    gemm_tanh_kernel<false><<<g, 256, 0, stream>>>(act1, W2, nullptr, part);
    combine_tanh_kernel<8><<<cgrid, 256, 0, stream>>>(part, b2, act2);
    gemm_tanh_kernel<false><<<g, 256, 0, stream>>>(act2, W3, nullptr, part);
    combine_tanh_kernel<8><<<cgrid, 256, 0, stream>>>(part, b3, act3);
    gemm_tanh_kernel<false><<<g, 256, 0, stream>>>(act3, W4, nullptr, part);
    combine_tanh_kernel<8><<<cgrid, 256, 0, stream>>>(part, b4, out);
  } else if (sk4) {
    dim3 g(4096 / BN, 512 / BM, 4);
    gemm_tanh_kernel<false><<<g, 256, 0, stream>>>(act1, W2, nullptr, part);
    combine_tanh_kernel<4><<<cgrid, 256, 0, stream>>>(part, b2, act2);
    gemm_tanh_kernel<false><<<g, 256, 0, stream>>>(act2, W3, nullptr, part);
    combine_tanh_kernel<4><<<cgrid, 256, 0, stream>>>(part, b3, act3);
    gemm_tanh_kernel<false><<<g, 256, 0, stream>>>(act3, W4, nullptr, part);
    combine_tanh_kernel<4><<<cgrid, 256, 0, stream>>>(part, b4, out);
  } else {
    dim3 g(4096 / BN, 512 / BM, 1);
    gemm_tanh_kernel<true><<<g, 256, 0, stream>>>(act1, W2, b2, act2);
    gemm_tanh_kernel<true><<<g, 256, 0, stream>>>(act2, W3, b3, act3);
    gemm_tanh_kernel<true><<<g, 256, 0, stream>>>(act3, W4, b4, out);
  }

  fid_dots_kernel<<<256, 256, 0, stream>>>(act1, act2, act3, out, D);
  finalize_kernel<<<1, 64, 0, stream>>>(D, wout);
}

// Round 4
// 425.313 us; speedup vs baseline: 1.0727x; 1.0727x over previous
//
#include <hip/hip_runtime.h>
#include <cmath>

// EstimatorQNNGen275: conv+sigmoid+mean -> 1-dim attention -> 4-layer tanh MLP
// (3x 512x4096x4096 GEMMs via fp16 MFMA, split-K=8, double-buffered pipeline)
// -> pairwise-fidelity graph.
//
// ws layout (bytes):
//   [0,2048)     c_buf (512 f32)
//   [2048,4096)  attn  (512 f32)
//   [4096,4736)  D     (10 dot accumulators, line-padded stride 16 f32)
//   [8192,+8MB)  act1 ; act2 ; act3 ; part (Z x 8MB split-K partials)

#define NEL (512 * 4096)

typedef float  floatx4 __attribute__((ext_vector_type(4)));
typedef _Float16 halfx8 __attribute__((ext_vector_type(8)));

// ---------------- conv + sigmoid + mean (float4) ----------------
__global__ __launch_bounds__(256) void conv_mean_kernel(
    const float* __restrict__ x, const float* __restrict__ cw,
    const float* __restrict__ cb, float* __restrict__ c_out)
{
  __shared__ float sbuf[4];
  const int b = blockIdx.x;
  const float w00 = cw[0], w01 = cw[1], w10 = cw[2], w11 = cw[3];
  const float bias = cb[0];
  const float* xb = x + (size_t)b * 128 * 128;
  float acc = 0.f;
  // 127 rows x 32 col-chunks of 4 outputs each
  for (int t = threadIdx.x; t < 127 * 32; t += 256) {
    const int i  = t >> 5;
    const int j0 = (t & 31) << 2;
    const float* pr0 = xb + i * 128 + j0;
    const float* pr1 = pr0 + 128;
    const float4 a4 = *reinterpret_cast<const float4*>(pr0);
    const float  a5 = pr0[4];
    const float4 b4 = *reinterpret_cast<const float4*>(pr1);
    const float  b5 = pr1[4];
    const float a[5] = {a4.x, a4.y, a4.z, a4.w, a5};
    const float bb[5] = {b4.x, b4.y, b4.z, b4.w, b5};
    #pragma unroll
    for (int m = 0; m < 4; ++m) {
      if (j0 + m < 127) {
        float v = w00 * a[m] + w01 * a[m + 1] + w10 * bb[m] + w11 * bb[m + 1] + bias;
        acc += 1.0f / (1.0f + __expf(-v));
      }
    }
  }
  #pragma unroll
  for (int off = 32; off > 0; off >>= 1) acc += __shfl_down(acc, off, 64);
  const int lane = threadIdx.x & 63, wv = threadIdx.x >> 6;
  if (lane == 0) sbuf[wv] = acc;
  __syncthreads();
  if (threadIdx.x == 0)
    c_out[b] = (sbuf[0] + sbuf[1] + sbuf[2] + sbuf[3]) * (1.0f / 16129.0f);
}

// ---------------- 1-dim attention ----------------
__global__ __launch_bounds__(64) void attn_kernel(
    const float* __restrict__ c, const float* __restrict__ rot,
    const float* __restrict__ ent, float* __restrict__ attn)
{
  const int i = blockIdx.x;
  const int lane = threadIdx.x;
  const float t = rot[0] * ent[0] * c[i];
  float vals[8], cj[8];
  float mx = -1e30f;
  #pragma unroll
  for (int u = 0; u < 8; ++u) {
    float cv = c[lane + u * 64];
    cj[u] = cv;
    vals[u] = t * cv;
    mx = fmaxf(mx, vals[u]);
  }
  #pragma unroll
  for (int off = 32; off > 0; off >>= 1) mx = fmaxf(mx, __shfl_down(mx, off, 64));
  mx = __shfl(mx, 0, 64);
  float se = 0.f, sw = 0.f;
  #pragma unroll
  for (int u = 0; u < 8; ++u) {
    float e = __expf(vals[u] - mx);
    se += e;
    sw += e * cj[u];
  }
  #pragma unroll
  for (int off = 32; off > 0; off >>= 1) {
    se += __shfl_down(se, off, 64);
    sw += __shfl_down(sw, off, 64);
  }
  if (lane == 0) attn[i] = sw / se;
}

// ---------------- layer 1 (outer product + tanh) ----------------
__global__ __launch_bounds__(256) void layer1_kernel(
    const float* __restrict__ attn, const float* __restrict__ W1,
    const float* __restrict__ b1, float* __restrict__ act1)
{
  const int o = blockIdx.x * 256 + threadIdx.x;
  const int i = blockIdx.y;
  act1[(size_t)i * 4096 + o] = tanhf(attn[i] * W1[o] + b1[o]);
}

// ---------------- fp16-MFMA GEMM (split-K, dbuf LDS pipeline) ----------------
// A: M x K fp32 row-major (M=512), W: N x K fp32 row-major (4096x4096).
// 128x128 tile, BK=32, 256 thr = 4 waves (2x2), wave = 64x64 = 4x4 mfma tiles.
// One barrier per K-iteration; global loads issued one full iter before use.
#define BM 128
#define BN 128
#define BK 32
#define LDK 40  // padded leading dim (halfs): bank-uniform for b128 r/w

template<bool FUSE>
__global__ __launch_bounds__(256, 4) void gemm_tanh_kernel(
    const float* __restrict__ A, const float* __restrict__ W,
    const float* __restrict__ bias, float* __restrict__ C)
{
  __shared__ _Float16 As[2][BM][LDK];
  __shared__ _Float16 Ws[2][BN][LDK];
  const int K = 4096, N = 4096;
  const int tid  = threadIdx.x;
  const int lane = tid & 63;
  const int wave = tid >> 6;
  const int wm = (wave >> 1) * 64;
  const int wn = (wave & 1) * 64;
  const int q  = lane >> 4;
  const int ml = lane & 15;
  const int tileM = blockIdx.y * BM;
  const int tileN = blockIdx.x * BN;
  const int Kslice = K / gridDim.z;
  const int kbeg = blockIdx.z * Kslice;
  const int kend = kbeg + Kslice;
  float* Cb = FUSE ? C : C + (size_t)blockIdx.z * NEL;

  floatx4 acc[4][4] = {};

  // staging map: thread handles rows r0 and r0+64, cols cc0..cc0+7 (fp32->fp16)
  const int r0  = tid >> 2;
  const int cc0 = (tid & 3) << 3;

  float4 pa[4], pw[4];
  auto load_tile = [&](int k0) {
    #pragma unroll
    for (int u = 0; u < 2; ++u) {
      const float* ap = A + (size_t)(tileM + r0 + u * 64) * K + k0 + cc0;
      pa[2 * u]     = *reinterpret_cast<const float4*>(ap);
      pa[2 * u + 1] = *reinterpret_cast<const float4*>(ap + 4);
      const float* wp = W + (size_t)(tileN + r0 + u * 64) * K + k0 + cc0;
      pw[2 * u]     = *reinterpret_cast<const float4*>(wp);
      pw[2 * u + 1] = *reinterpret_cast<const float4*>(wp + 4);
    }
  };
  auto store_tile = [&](int buf) {
    #pragma unroll
    for (int u = 0; u < 2; ++u) {
      halfx8 ha = { (_Float16)pa[2*u].x, (_Float16)pa[2*u].y,
                    (_Float16)pa[2*u].z, (_Float16)pa[2*u].w,
                    (_Float16)pa[2*u+1].x, (_Float16)pa[2*u+1].y,
                    (_Float16)pa[2*u+1].z, (_Float16)pa[2*u+1].w };
      *reinterpret_cast<halfx8*>(&As[buf][r0 + u * 64][cc0]) = ha;
      halfx8 hw = { (_Float16)pw[2*u].x, (_Float16)pw[2*u].y,
                    (_Float16)pw[2*u].z, (_Float16)pw[2*u].w,
                    (_Float16)pw[2*u+1].x, (_Float16)pw[2*u+1].y,
                    (_Float16)pw[2*u+1].z, (_Float16)pw[2*u+1].w };
      *reinterpret_cast<halfx8*>(&Ws[buf][r0 + u * 64][cc0]) = hw;
    }
  };

  // prologue: fill buf 0
  load_tile(kbeg);
  store_tile(0);
  int cur = 0;

  for (int k0 = kbeg; k0 < kend; k0 += BK) {
    const bool more = (k0 + BK < kend);
    if (more) load_tile(k0 + BK);   // in flight across barrier + MFMA below
    __syncthreads();                // buf[cur] visible; prior readers of buf[cur^1] done

    halfx8 af[4], bf[4];
    #pragma unroll
    for (int i = 0; i < 4; ++i)
      af[i] = *reinterpret_cast<const halfx8*>(&As[cur][wm + i * 16 + ml][q * 8]);
    #pragma unroll
    for (int j = 0; j < 4; ++j)
      bf[j] = *reinterpret_cast<const halfx8*>(&Ws[cur][wn + j * 16 + ml][q * 8]);

    #pragma unroll
    for (int i = 0; i < 4; ++i)
      #pragma unroll
      for (int j = 0; j < 4; ++j)
        acc[i][j] = __builtin_amdgcn_mfma_f32_16x16x32_f16(af[i], bf[j], acc[i][j], 0, 0, 0);

    if (more) store_tile(cur ^ 1);  // vmcnt wait lands ~1 full iter after issue
    cur ^= 1;
  }

  // C/D layout: col=lane&15, row=(lane>>4)*4+reg
  #pragma unroll
  for (int i = 0; i < 4; ++i) {
    const int row0 = tileM + wm + i * 16 + q * 4;
    #pragma unroll
    for (int j = 0; j < 4; ++j) {
      const int col = tileN + wn + j * 16 + ml;
      if (FUSE) {
        const float bv = bias[col];
        #pragma unroll
        for (int r = 0; r < 4; ++r)
          Cb[(size_t)(row0 + r) * N + col] = tanhf(acc[i][j][r] + bv);
      } else {
        #pragma unroll
        for (int r = 0; r < 4; ++r)
          Cb[(size_t)(row0 + r) * N + col] = acc[i][j][r];
      }
    }
  }
}

// ---------------- split-K combine: sum S slices + bias + tanh ----------------
template<int S>
__global__ __launch_bounds__(256) void combine_tanh_kernel(
    const float* __restrict__ part, const float* __restrict__ bias,
    float* __restrict__ outp)
{
  const int i4 = blockIdx.x * 256 + threadIdx.x;  // < NEL/4
  const floatx4* p4 = (const floatx4*)part;
  floatx4 s = p4[i4];
  #pragma unroll
  for (int z = 1; z < S; ++z) s += p4[(size_t)z * (NEL / 4) + i4];
  const floatx4 bv = ((const floatx4*)bias)[i4 & 1023];
  floatx4 o;
  #pragma unroll
  for (int r = 0; r < 4; ++r) o[r] = tanhf(s[r] + bv[r]);
  ((floatx4*)outp)[i4] = o;
}

// ---------------- fid pairwise dots (low-contention) ----------------
__global__ __launch_bounds__(256) void fid_dots_kernel(
    const float* __restrict__ a1, const float* __restrict__ a2,
    const float* __restrict__ a3, const float* __restrict__ a4,
    float* __restrict__ D)
{
  __shared__ float sred[4][10];
  float s[10] = {0, 0, 0, 0, 0, 0, 0, 0, 0, 0};
  const int n4 = NEL / 4;
  const int stride = gridDim.x * blockDim.x;
  const floatx4* p1 = (const floatx4*)a1;
  const floatx4* p2 = (const floatx4*)a2;
  const floatx4* p3 = (const floatx4*)a3;
  const floatx4* p4 = (const floatx4*)a4;
  for (int i = blockIdx.x * 256 + threadIdx.x; i < n4; i += stride) {
    floatx4 v1 = p1[i], v2 = p2[i], v3 = p3[i], v4 = p4[i];
    #pragma unroll
    for (int r = 0; r < 4; ++r) {
      s[0] += v1[r] * v1[r]; s[1] += v1[r] * v2[r]; s[2] += v1[r] * v3[r];
      s[3] += v1[r] * v4[r]; s[4] += v2[r] * v2[r]; s[5] += v2[r] * v3[r];
      s[6] += v2[r] * v4[r]; s[7] += v3[r] * v3[r]; s[8] += v3[r] * v4[r];
      s[9] += v4[r] * v4[r];
    }
  }
  const int lane = threadIdx.x & 63, wv = threadIdx.x >> 6;
  #pragma unroll
  for (int p = 0; p < 10; ++p) {
    float v = s[p];
    #pragma unroll
    for (int off = 32; off > 0; off >>= 1) v += __shfl_down(v, off, 64);
    if (lane == 0) sred[wv][p] = v;
  }
  __syncthreads();
  if (threadIdx.x < 10) {
    float v = sred[0][threadIdx.x] + sred[1][threadIdx.x] +
              sred[2][threadIdx.x] + sred[3][threadIdx.x];
    atomicAdd(&D[threadIdx.x * 16], v);
  }
}

// ---------------- finalize graph weights ----------------
__global__ void finalize_kernel(const float* __restrict__ D, float* __restrict__ wout)
{
  const int i = threadIdx.x;
  if (i >= 16) return;
  const int p = i >> 2, qq = i & 3;
  const int a = p < qq ? p : qq;
  const int b = p < qq ? qq : p;
  const int base[4] = {0, 4, 7, 9};
  const float dpq = D[(base[a] + (b - a)) * 16];
  const float npv = sqrtf(D[base[p] * 16]) + 1e-12f;
  const float nqv = sqrtf(D[base[qq] * 16]) + 1e-12f;
  const float ch = dpq / (npv * nqv);
  const float fid = ch * ch;
  wout[i] = (fid >= 0.8f && p != qq) ? 1.0f : 0.0f;
}

extern "C" void kernel_launch(void* const* d_in, const int* in_sizes, int n_in,
                              void* d_out, int out_size, void* d_ws, size_t ws_size,
                              hipStream_t stream)
{
  const float* x   = (const float*)d_in[0];
  const float* cw  = (const float*)d_in[1];
  const float* cb  = (const float*)d_in[2];
  const float* rot = (const float*)d_in[3];
  const float* ent = (const float*)d_in[4];
  const float* W1  = (const float*)d_in[5];
  const float* b1  = (const float*)d_in[6];
  const float* W2  = (const float*)d_in[7];
  const float* b2  = (const float*)d_in[8];
  const float* W3  = (const float*)d_in[9];
  const float* b3  = (const float*)d_in[10];
  const float* W4  = (const float*)d_in[11];
  const float* b4  = (const float*)d_in[12];
  float* out = (float*)d_out;

  char*  ws    = (char*)d_ws;
  float* c_buf = (float*)(ws + 0);
  float* attn  = (float*)(ws + 2048);
  float* D     = (float*)(ws + 4096);
  float* act1  = (float*)(ws + 8192);
  float* act2  = act1 + NEL;
  float* act3  = act2 + NEL;
  float* part  = act3 + NEL;  // Z x NEL fp32 split-K partials
  float* wout  = out + NEL;

  const size_t base_need = 8192 + (size_t)3 * NEL * 4;
  const bool sk8 = ws_size >= base_need + (size_t)8 * NEL * 4;
  const bool sk4 = ws_size >= base_need + (size_t)4 * NEL * 4;

  hipMemsetAsync(D, 0, 10 * 16 * sizeof(float), stream);
  conv_mean_kernel<<<512, 256, 0, stream>>>(x, cw, cb, c_buf);
  attn_kernel<<<512, 64, 0, stream>>>(c_buf, rot, ent, attn);
  layer1_kernel<<<dim3(16, 512), 256, 0, stream>>>(attn, W1, b1, act1);

  const int cgrid = NEL / 4 / 256;
  if (sk8) {
    dim3 g(4096 / BN, 512 / BM, 8);  // 1024 blocks -> 4 blocks/CU
    gemm_tanh_kernel<false><<<g, 256, 0, stream>>>(act1, W2, nullptr, part);
    combine_tanh_kernel<8><<<cgrid, 256, 0, stream>>>(part, b2, act2);
    gemm_tanh_kernel<false><<<g, 256, 0, stream>>>(act2, W3, nullptr, part);
    combine_tanh_kernel<8><<<cgrid, 256, 0, stream>>>(part, b3, act3);
    gemm_tanh_kernel<false><<<g, 256, 0, stream>>>(act3, W4, nullptr, part);
    combine_tanh_kernel<8><<<cgrid, 256, 0, stream>>>(part, b4, out);
  } else if (sk4) {
    dim3 g(4096 / BN, 512 / BM, 4);
    gemm_tanh_kernel<false><<<g, 256, 0, stream>>>(act1, W2, nullptr, part);
    combine_tanh_kernel<4><<<cgrid, 256, 0, stream>>>(part, b2, act2);
    gemm_tanh_kernel<false><<<g, 256, 0, stream>>>(act2, W3, nullptr, part);
    combine_tanh_kernel<4><<<cgrid, 256, 0, stream>>>(part, b3, act3);
    gemm_tanh_kernel<false><<<g, 256, 0, stream>>>(act3, W4, nullptr, part);
    combine_tanh_kernel<4><<<cgrid, 256, 0, stream>>>(part, b4, out);
  } else {
    dim3 g(4096 / BN, 512 / BM, 1);
    gemm_tanh_kernel<true><<<g, 256, 0, stream>>>(act1, W2, b2, act2);
    gemm_tanh_kernel<true><<<g, 256, 0, stream>>>(act2, W3, b3, act3);
    gemm_tanh_kernel<true><<<g, 256, 0, stream>>>(act3, W4, b4, out);
  }

  fid_dots_kernel<<<256, 256, 0, stream>>>(act1, act2, act3, out, D);
  finalize_kernel<<<1, 64, 0, stream>>>(D, wout);
}